// Round 1
// baseline (329.393 us; speedup 1.0000x reference)
//
#include <hip/hip_runtime.h>

#define TILE 4  // points per thread (float4)

__global__ __launch_bounds__(256) void mrt_kernel(
    const float* __restrict__ f,
    const float* __restrict__ j_w1, const float* __restrict__ j_b1,
    const float* __restrict__ j_w2, const float* __restrict__ j_b2,
    const float* __restrict__ n_w1, const float* __restrict__ n_b1,
    const float* __restrict__ n_w2, const float* __restrict__ n_b2,
    const float* __restrict__ Mg, const float* __restrict__ Minvg,
    float* __restrict__ out, int n2)
{
    // Packed weights: sW1[o][i] = {w1j[o][i], w1j[o][FLIP[i]], w1n[o][i], w1n[o][FLIP[i]]}
    // (16B-aligned quads -> single ds_read_b128 broadcast per (o,i))
    __shared__ float sW1[24][9][4];
    __shared__ float sMt[9][9];    // sMt[i][r] = M[r][i]  (transposed: column access)
    __shared__ float sMinv[9][9];  // row-major
    __shared__ float sB[24][4];    // {b1j, b1n, w2j, w2n}
    __shared__ float sb2[2];       // {b2j, b2n}

    const int tid = threadIdx.x;
    const int FLIPc[9] = {0, 2, 1, 5, 4, 3, 6, 8, 7};

    for (int t = tid; t < 216; t += 256) {
        int o = t / 9, i = t % 9;
        float wj = j_w1[t], wn = n_w1[t];
        sW1[o][i][0] = wj;
        sW1[o][i][2] = wn;
        // want sW1[o][p][1] = w1j[o][FLIP[p]]; FLIP is an involution:
        sW1[o][FLIPc[i]][1] = wj;
        sW1[o][FLIPc[i]][3] = wn;
    }
    for (int t = tid; t < 81; t += 256) {
        int r = t / 9, c = t % 9;
        sMt[c][r]   = Mg[t];
        sMinv[r][c] = Minvg[t];
    }
    if (tid < 24) {
        sB[tid][0] = j_b1[tid];
        sB[tid][1] = n_b1[tid];
        sB[tid][2] = j_w2[tid];
        sB[tid][3] = n_w2[tid];
    }
    if (tid == 0) { sb2[0] = j_b2[0]; sb2[1] = n_b2[0]; }
    __syncthreads();

    const long base = ((long)blockIdx.x * blockDim.x + tid) * TILE;
    if (base >= n2) return;

    // ---- m = M @ f (per point) ----
    float m[9][TILE];
    #pragma unroll
    for (int r = 0; r < 9; ++r)
        #pragma unroll
        for (int k = 0; k < TILE; ++k) m[r][k] = 0.0f;

    #pragma unroll
    for (int i = 0; i < 9; ++i) {
        float4 v = *reinterpret_cast<const float4*>(f + (size_t)i * n2 + base);
        float vv[TILE] = {v.x, v.y, v.z, v.w};
        #pragma unroll
        for (int r = 0; r < 9; ++r) {
            float w = sMt[i][r];
            #pragma unroll
            for (int k = 0; k < TILE; ++k)
                m[r][k] = fmaf(w, vv[k], m[r][k]);
        }
    }

    // ---- 4 MLP hidden evals fused: j(mt), j(mtf), n(mt), n(mtf) ----
    float aj[TILE], ajf[TILE], an1[TILE], an2[TILE];
    #pragma unroll
    for (int k = 0; k < TILE; ++k) { aj[k] = 0.f; ajf[k] = 0.f; an1[k] = 0.f; an2[k] = 0.f; }

    #pragma unroll 3
    for (int o = 0; o < 24; ++o) {
        float b1j_ = sB[o][0], b1n_ = sB[o][1];
        float hj[TILE], hjf[TILE], hn[TILE], hnf[TILE];
        #pragma unroll
        for (int k = 0; k < TILE; ++k) { hj[k] = b1j_; hjf[k] = b1j_; hn[k] = b1n_; hnf[k] = b1n_; }
        #pragma unroll
        for (int i = 0; i < 9; ++i) {
            float wj  = sW1[o][i][0];
            float wjf = sW1[o][i][1];
            float wn  = sW1[o][i][2];
            float wnf = sW1[o][i][3];
            #pragma unroll
            for (int k = 0; k < TILE; ++k) {
                float x = m[i][k];
                hj[k]  = fmaf(wj,  x, hj[k]);
                hjf[k] = fmaf(wjf, x, hjf[k]);
                hn[k]  = fmaf(wn,  x, hn[k]);
                hnf[k] = fmaf(wnf, x, hnf[k]);
            }
        }
        float w2j_ = sB[o][2], w2n_ = sB[o][3];
        #pragma unroll
        for (int k = 0; k < TILE; ++k) {
            aj[k]  = fmaf(fmaxf(hj[k],  0.f), w2j_, aj[k]);
            ajf[k] = fmaf(fmaxf(hjf[k], 0.f), w2j_, ajf[k]);
            an1[k] = fmaf(fmaxf(hn[k],  0.f), w2n_, an1[k]);
            an2[k] = fmaf(fmaxf(hnf[k], 0.f), w2n_, an2[k]);
        }
    }

    const float b2j_ = sb2[0], b2n_ = sb2[1];

    // ---- taus, meq, relaxation ----
    #pragma unroll
    for (int k = 0; k < TILE; ++k) {
        float tjx = 0.5f + expf(aj[k]  + b2j_);
        float tjy = 0.5f + expf(ajf[k] + b2j_);
        float tn  = 0.5f + expf((an1[k] + b2n_) + (an2[k] + b2n_));

        float rho = m[0][k], jx = m[1][k], jy = m[2][k];
        // components 0..2: meq == m -> unchanged
        m[3][k] = m[3][k] - (m[3][k] - jx * jx / rho) / 0.7f;
        m[4][k] = m[4][k] - (m[4][k] - jx * jy / rho) / 0.7f;
        m[5][k] = m[5][k] - (m[5][k] - jy * jy / rho) / 0.7f;
        m[6][k] = m[6][k] - m[6][k] / tn;
        m[7][k] = m[7][k] - m[7][k] / tjx;
        m[8][k] = m[8][k] - m[8][k] / tjy;
    }

    // ---- out = Minv @ m_post ----
    #pragma unroll
    for (int r = 0; r < 9; ++r) {
        float o0[TILE];
        #pragma unroll
        for (int k = 0; k < TILE; ++k) o0[k] = 0.0f;
        #pragma unroll
        for (int j = 0; j < 9; ++j) {
            float w = sMinv[r][j];
            #pragma unroll
            for (int k = 0; k < TILE; ++k)
                o0[k] = fmaf(w, m[j][k], o0[k]);
        }
        float4 vv = make_float4(o0[0], o0[1], o0[2], o0[3]);
        *reinterpret_cast<float4*>(out + (size_t)r * n2 + base) = vv;
    }
}

extern "C" void kernel_launch(void* const* d_in, const int* in_sizes, int n_in,
                              void* d_out, int out_size, void* d_ws, size_t ws_size,
                              hipStream_t stream) {
    const float* f    = (const float*)d_in[0];
    const float* j_w1 = (const float*)d_in[1];
    const float* j_b1 = (const float*)d_in[2];
    const float* j_w2 = (const float*)d_in[3];
    const float* j_b2 = (const float*)d_in[4];
    const float* n_w1 = (const float*)d_in[5];
    const float* n_b1 = (const float*)d_in[6];
    const float* n_w2 = (const float*)d_in[7];
    const float* n_b2 = (const float*)d_in[8];
    const float* Mg   = (const float*)d_in[9];
    const float* Minv = (const float*)d_in[10];
    float* out = (float*)d_out;

    const int n2 = in_sizes[0] / 9;              // 2048*2048 points
    const int pts_per_block = 256 * TILE;
    const int grid = (n2 + pts_per_block - 1) / pts_per_block;

    mrt_kernel<<<grid, 256, 0, stream>>>(f, j_w1, j_b1, j_w2, j_b2,
                                         n_w1, n_b1, n_w2, n_b2,
                                         Mg, Minv, out, n2);
}

// Round 2
// 300.214 us; speedup vs baseline: 1.0972x; 1.0972x over previous
//
#include <hip/hip_runtime.h>

typedef float f32x2 __attribute__((ext_vector_type(2)));

__device__ __forceinline__ f32x2 splat2(float s) { f32x2 v; v.x = s; v.y = s; return v; }
__device__ __forceinline__ f32x2 pfma(f32x2 a, f32x2 b, f32x2 c) { return __builtin_elementwise_fma(a, b, c); }
__device__ __forceinline__ f32x2 pfmas(float a, f32x2 b, f32x2 c) { return __builtin_elementwise_fma(splat2(a), b, c); }
__device__ __forceinline__ f32x2 prelu(f32x2 a) { return __builtin_elementwise_max(a, splat2(0.0f)); }

#define NP 2  // float2 pairs per thread (4 points)

__global__ __launch_bounds__(256) void mrt_kernel(
    const float* __restrict__ f,
    const float* __restrict__ j_w1, const float* __restrict__ j_b1,
    const float* __restrict__ j_w2, const float* __restrict__ j_b2,
    const float* __restrict__ n_w1, const float* __restrict__ n_b1,
    const float* __restrict__ n_w2, const float* __restrict__ n_b2,
    const float* __restrict__ Mg, const float* __restrict__ Minvg,
    float* __restrict__ out, int n2)
{
    // FLIP = [0,2,1,5,4,3,6,8,7]: fixed {0,4,6}, pairs (1,2),(3,5),(7,8).
    // W1 decomposed under FLIP: h = s + a, h_flip = s - a.
    // sW[o] layout (20 floats, 16B-aligned rows, 80B stride):
    //   [0..2]  j: w at cols 0,4,6      [3..5] j: (w[p1]+w[p2])/2
    //   [6..8]  j: (w[p1]-w[p2])/2      [9]    j: b1
    //   [10..19] same for n-MLP
    __shared__ __align__(16) float sW[24][20];
    __shared__ float sW2[24][2];   // {w2j, w2n}
    __shared__ float sMt[9][9];    // sMt[i][r] = M[r][i]
    __shared__ float sMv[9][9];    // Minv row-major
    __shared__ float sb2[2];

    const int tid = threadIdx.x;

    if (tid < 48) {
        const int o = tid >> 1;        // 0..23
        const int which = tid & 1;     // 0 = j-MLP, 1 = n-MLP
        const float* w1 = which ? n_w1 : j_w1;
        const float* b1 = which ? n_b1 : j_b1;
        float w[9];
        #pragma unroll
        for (int i = 0; i < 9; ++i) w[i] = w1[o * 9 + i];
        float* dst = &sW[o][which * 10];
        dst[0] = w[0]; dst[1] = w[4]; dst[2] = w[6];
        dst[3] = 0.5f * (w[1] + w[2]); dst[4] = 0.5f * (w[3] + w[5]); dst[5] = 0.5f * (w[7] + w[8]);
        dst[6] = 0.5f * (w[1] - w[2]); dst[7] = 0.5f * (w[3] - w[5]); dst[8] = 0.5f * (w[7] - w[8]);
        dst[9] = b1[o];
        if (which == 0) { sW2[o][0] = j_w2[o]; sW2[o][1] = n_w2[o]; }
    }
    for (int t = tid; t < 81; t += 256) {
        sMt[t % 9][t / 9] = Mg[t];
        sMv[t / 9][t % 9] = Minvg[t];
    }
    if (tid == 0) { sb2[0] = j_b2[0]; sb2[1] = n_b2[0]; }
    __syncthreads();

    const long base = ((long)blockIdx.x * blockDim.x + tid) * (2 * NP);
    if (base >= n2) return;

    // ---- m = M @ f ----
    f32x2 m[NP][9];
    #pragma unroll
    for (int p = 0; p < NP; ++p)
        #pragma unroll
        for (int r = 0; r < 9; ++r) m[p][r] = splat2(0.0f);

    #pragma unroll
    for (int i = 0; i < 9; ++i) {
        const float4 v = *reinterpret_cast<const float4*>(f + (size_t)i * n2 + base);
        f32x2 v0; v0.x = v.x; v0.y = v.y;
        f32x2 v1; v1.x = v.z; v1.y = v.w;
        #pragma unroll
        for (int r = 0; r < 9; ++r) {
            const float w = sMt[i][r];
            m[0][r] = pfmas(w, v0, m[0][r]);
            m[1][r] = pfmas(w, v1, m[1][r]);
        }
    }

    // ---- reduced input vector under FLIP symmetry ----
    f32x2 tv[NP][9];
    #pragma unroll
    for (int p = 0; p < NP; ++p) {
        tv[p][0] = m[p][0]; tv[p][1] = m[p][4]; tv[p][2] = m[p][6];
        tv[p][3] = m[p][1] + m[p][2]; tv[p][4] = m[p][3] + m[p][5]; tv[p][5] = m[p][7] + m[p][8];
        tv[p][6] = m[p][1] - m[p][2]; tv[p][7] = m[p][3] - m[p][5]; tv[p][8] = m[p][7] - m[p][8];
    }

    // ---- fused hidden layer: j(mt), j(mtf), n(mt), n(mtf) ----
    f32x2 accj[NP], accjf[NP], accn[NP];
    #pragma unroll
    for (int p = 0; p < NP; ++p) { accj[p] = splat2(0.f); accjf[p] = splat2(0.f); accn[p] = splat2(0.f); }

    #pragma unroll 4
    for (int o = 0; o < 24; ++o) {
        const float4* pw = reinterpret_cast<const float4*>(sW[o]);
        const float4 c0 = pw[0], c1 = pw[1], c2 = pw[2], c3 = pw[3], c4 = pw[4];
        const float w2j = sW2[o][0], w2n = sW2[o][1];
        #pragma unroll
        for (int p = 0; p < NP; ++p) {
            f32x2 s = splat2(c2.y);                 // b1j
            s = pfmas(c0.x, tv[p][0], s);
            s = pfmas(c0.y, tv[p][1], s);
            s = pfmas(c0.z, tv[p][2], s);
            s = pfmas(c0.w, tv[p][3], s);
            s = pfmas(c1.x, tv[p][4], s);
            s = pfmas(c1.y, tv[p][5], s);
            f32x2 a = splat2(c1.z) * tv[p][6];
            a = pfmas(c1.w, tv[p][7], a);
            a = pfmas(c2.x, tv[p][8], a);
            const f32x2 hj  = prelu(s + a);
            const f32x2 hjf = prelu(s - a);

            f32x2 sn = splat2(c4.w);                // b1n
            sn = pfmas(c2.z, tv[p][0], sn);
            sn = pfmas(c2.w, tv[p][1], sn);
            sn = pfmas(c3.x, tv[p][2], sn);
            sn = pfmas(c3.y, tv[p][3], sn);
            sn = pfmas(c3.z, tv[p][4], sn);
            sn = pfmas(c3.w, tv[p][5], sn);
            f32x2 an_ = splat2(c4.x) * tv[p][6];
            an_ = pfmas(c4.y, tv[p][7], an_);
            an_ = pfmas(c4.z, tv[p][8], an_);
            const f32x2 hn  = prelu(sn + an_);
            const f32x2 hnf = prelu(sn - an_);

            accj[p]  = pfmas(w2j, hj,  accj[p]);
            accjf[p] = pfmas(w2j, hjf, accjf[p]);
            accn[p]  = pfmas(w2n, hn + hnf, accn[p]);
        }
    }

    // ---- taus + relaxation (in place on m) ----
    const float b2j = sb2[0], b2n = sb2[1];
    const f32x2 Cs = splat2(1.0f / 0.7f);
    #pragma unroll
    for (int p = 0; p < NP; ++p) {
        const f32x2 aj  = accj[p]  + splat2(b2j);
        const f32x2 ajf = accjf[p] + splat2(b2j);
        const f32x2 an  = accn[p]  + splat2(2.0f * b2n);
        f32x2 rt7, rt8, rt6, rrho;
        rt7.x = __builtin_amdgcn_rcpf(0.5f + __expf(aj.x));
        rt7.y = __builtin_amdgcn_rcpf(0.5f + __expf(aj.y));
        rt8.x = __builtin_amdgcn_rcpf(0.5f + __expf(ajf.x));
        rt8.y = __builtin_amdgcn_rcpf(0.5f + __expf(ajf.y));
        rt6.x = __builtin_amdgcn_rcpf(0.5f + __expf(an.x));
        rt6.y = __builtin_amdgcn_rcpf(0.5f + __expf(an.y));
        rrho.x = __builtin_amdgcn_rcpf(m[p][0].x);
        rrho.y = __builtin_amdgcn_rcpf(m[p][0].y);
        const f32x2 jx = m[p][1], jy = m[p][2];
        m[p][3] = m[p][3] - (m[p][3] - jx * jx * rrho) * Cs;
        m[p][4] = m[p][4] - (m[p][4] - jx * jy * rrho) * Cs;
        m[p][5] = m[p][5] - (m[p][5] - jy * jy * rrho) * Cs;
        m[p][6] = m[p][6] - m[p][6] * rt6;
        m[p][7] = m[p][7] - m[p][7] * rt7;
        m[p][8] = m[p][8] - m[p][8] * rt8;
    }

    // ---- out = Minv @ m_post ----
    #pragma unroll
    for (int r = 0; r < 9; ++r) {
        f32x2 o0 = splat2(0.f), o1 = splat2(0.f);
        #pragma unroll
        for (int j = 0; j < 9; ++j) {
            const float w = sMv[r][j];
            o0 = pfmas(w, m[0][j], o0);
            o1 = pfmas(w, m[1][j], o1);
        }
        const float4 vv = make_float4(o0.x, o0.y, o1.x, o1.y);
        *reinterpret_cast<float4*>(out + (size_t)r * n2 + base) = vv;
    }
}

extern "C" void kernel_launch(void* const* d_in, const int* in_sizes, int n_in,
                              void* d_out, int out_size, void* d_ws, size_t ws_size,
                              hipStream_t stream) {
    const float* f    = (const float*)d_in[0];
    const float* j_w1 = (const float*)d_in[1];
    const float* j_b1 = (const float*)d_in[2];
    const float* j_w2 = (const float*)d_in[3];
    const float* j_b2 = (const float*)d_in[4];
    const float* n_w1 = (const float*)d_in[5];
    const float* n_b1 = (const float*)d_in[6];
    const float* n_w2 = (const float*)d_in[7];
    const float* n_b2 = (const float*)d_in[8];
    const float* Mg   = (const float*)d_in[9];
    const float* Minv = (const float*)d_in[10];
    float* out = (float*)d_out;

    const int n2 = in_sizes[0] / 9;
    const int pts_per_block = 256 * 2 * NP;
    const int grid = (n2 + pts_per_block - 1) / pts_per_block;

    mrt_kernel<<<grid, 256, 0, stream>>>(f, j_w1, j_b1, j_w2, j_b2,
                                         n_w1, n_b1, n_w2, n_b2,
                                         Mg, Minv, out, n2);
}